// Round 7
// baseline (1417.008 us; speedup 1.0000x reference)
//
#include <hip/hip_runtime.h>
#include <stdint.h>

#define Tdim 128
#define Bdim 32
#define Sdim 64
#define Fdim 256
#define NCONS 32
#define NPROD 1024

typedef unsigned short u16;
typedef short bf16x8 __attribute__((ext_vector_type(8)));
typedef float f32x4 __attribute__((ext_vector_type(4)));

#define K2     2.8853900817779268f   /* 2*log2(e) */
#define LOG2E  1.4426950408889634f

__device__ __forceinline__ u16 f2b(float f){
  union { float f; uint32_t u; } v; v.f = f;
  uint32_t u = v.u;
  if ((u & 0x7fffffffu) > 0x7f800000u) return (u16)0x7fc0;
  uint32_t r = (u + 0x7fffu + ((u >> 16) & 1u)) >> 16;
  return (u16)r;
}
__device__ __forceinline__ float b2f(u16 h){
  union { uint32_t u; float f; } v; v.u = ((uint32_t)h) << 16; return v.f;
}
__device__ __forceinline__ float b2f_lo(uint32_t w){
  union { uint32_t u; float f; } v; v.u = w << 16; return v.f;
}
__device__ __forceinline__ float b2f_hi(uint32_t w){
  union { uint32_t u; float f; } v; v.u = w & 0xffff0000u; return v.f;
}
__device__ __forceinline__ uint32_t pack2(float a, float b){
  return (uint32_t)f2b(a) | ((uint32_t)f2b(b) << 16);
}
__device__ __forceinline__ uint4 pack8(const float4 a, const float4 b){
  uint4 r;
  r.x = pack2(a.x, a.y); r.y = pack2(a.z, a.w);
  r.z = pack2(b.x, b.y); r.w = pack2(b.z, b.w);
  return r;
}

// Raw workgroup barrier WITHOUT the vmcnt(0) drain __syncthreads forces.
// (Correctness-proven on this kernel family: scan4/scan6/combined passed.)
__device__ __forceinline__ void bar_lds(){
  asm volatile("s_waitcnt lgkmcnt(0)" ::: "memory");
  __builtin_amdgcn_s_barrier();
  asm volatile("" ::: "memory");
}

// ===========================================================================
// FAST PATH (workspace: P 134MB + q 1MB + Wt 128KB + flags 8KB)
// ===========================================================================

// ---- Kernel 0: Wt[g][f] = bf16(W[f][g]) + zero the 2048 producer flags.
__global__ __launch_bounds__(256) void kt_transpose_cvt(const float* __restrict__ Wg,
                                                        u16* __restrict__ Wt,
                                                        int* __restrict__ flags){
  __shared__ u16 tile[64*66];
  int bx = blockIdx.x;            // 16 blocks: 4x4 tiles of 64x64
  int ti = bx >> 2, tj = bx & 3;
  int t = threadIdx.x;
  int gid = bx*256 + t;
  if (gid < NCONS*64) flags[gid] = 0;
#pragma unroll
  for (int i = 0; i < 16; ++i){
    int e = t*16 + i;
    int r = e >> 6, c = e & 63;
    tile[r*66 + c] = f2b(Wg[(ti*64 + r)*256 + tj*64 + c]);
  }
  __syncthreads();
#pragma unroll
  for (int i = 0; i < 16; ++i){
    int e = t*16 + i;
    int r = e >> 6, c = e & 63;   // r = g-local, c = f-local
    Wt[(tj*64 + r)*256 + ti*64 + c] = tile[c*66 + r];
  }
}

// ---- Kernel 1: COMBINED producer/consumer, single launch.
//  blocks 0..31   : consumer = scan body, deep prefetch, ILP'd reductions.
//  blocks 32..1055: producer = two 512-thread gemm halves (tq2-major order),
//                   release-publish flags[b*64+tq2] after full drain.
//  LDS union 112KB => 1 block/CU => consumers own their CUs exclusively.
__global__ __launch_bounds__(1024, 4) void kt_combined(
    const float* __restrict__ Xg, const u16* __restrict__ Wt,
    const float* __restrict__ Wlg, const float* __restrict__ Wcg,
    const float* __restrict__ Wlcg, const float* __restrict__ blg,
    const float* __restrict__ biasg, const float* __restrict__ ug,
    u16* __restrict__ Pg, float* __restrict__ qg,
    int* __restrict__ flags, float* __restrict__ out)
{
  __shared__ union ShMem {
    struct {                         // producer view (111.6 KB)
      u16 Ws[2][256*72];
      u16 Xs[2][128*72];
      float Wls[256];
    } p;
    struct {                         // consumer view (25.1 KB)
      float ctx[256], bbr[256], ur[256], wlc[256];
      float pp[64*17];
      float attp[16*260];
      float glc[4];
    } c;
  } sh;

  const int tid = threadIdx.x;

  if (blockIdx.x >= NCONS){
    // ================= PRODUCER =================
    const int p   = blockIdx.x - NCONS;
    const int h   = tid >> 9;          // half 0/1
    const int t   = tid & 511;
    const int hg  = p*2 + h;           // 0..2047
    const int bb  = hg & 31;
    const int tq2 = hg >> 5;           // 0..63
    const int r0  = bb*8192 + tq2*128;
    u16* __restrict__ Ws = sh.p.Ws[h];
    u16* __restrict__ Xs = sh.p.Xs[h];
    float* Wls = sh.p.Wls;
    if (tid < 256) Wls[tid] = Wlg[tid];
    const int lane = t & 63, wv = t >> 6;
    const int goff = (wv & 3)*64, roff = (wv >> 2)*64;
    const int fr = lane & 15, fq = lane >> 4;
    f32x4 acc[4][4];
#pragma unroll
    for (int a = 0; a < 4; ++a)
#pragma unroll
      for (int b2 = 0; b2 < 4; ++b2)
        acc[a][b2] = (f32x4){0.f,0.f,0.f,0.f};
    float qacc = 0.f;

    for (int kk = 0; kk < 4; ++kk){
      int k0 = kk*64;
      __syncthreads();   // protect LDS reuse; also publishes Wls on kk=0
#pragma unroll
      for (int uu = 0; uu < 4; ++uu){
        int unit = uu*512 + t;
        int row = unit >> 3, cc = unit & 7;
        *(uint4*)&Ws[row*72 + cc*8] = *(const uint4*)&Wt[row*256 + k0 + cc*8];
      }
#pragma unroll
      for (int uu = 0; uu < 2; ++uu){
        int unit = uu*512 + t;
        int row = unit >> 3, cc = unit & 7;
        const float4* xp = (const float4*)&Xg[(size_t)(r0+row)*256 + k0 + cc*8];
        *(uint4*)&Xs[row*72 + cc*8] = pack8(xp[0], xp[1]);
      }
      __syncthreads();
      if (t < 128){
        int r = t;
#pragma unroll
        for (int cc = 0; cc < 8; ++cc){
          uint4 xv = *(const uint4*)&Xs[r*72 + cc*8];
          const uint32_t* xw = (const uint32_t*)&xv;
#pragma unroll
          for (int q2 = 0; q2 < 4; ++q2){
            qacc = fmaf(b2f_lo(xw[q2]), Wls[k0 + cc*8 + 2*q2],     qacc);
            qacc = fmaf(b2f_hi(xw[q2]), Wls[k0 + cc*8 + 2*q2 + 1], qacc);
          }
        }
      }
#pragma unroll
      for (int ks = 0; ks < 64; ks += 32){
        bf16x8 af[4], bf_[4];
#pragma unroll
        for (int mi = 0; mi < 4; ++mi)
          af[mi] = *(const bf16x8*)&Ws[(goff + mi*16 + fr)*72 + ks + fq*8];
#pragma unroll
        for (int ni = 0; ni < 4; ++ni)
          bf_[ni] = *(const bf16x8*)&Xs[(roff + ni*16 + fr)*72 + ks + fq*8];
#pragma unroll
        for (int mi = 0; mi < 4; ++mi)
#pragma unroll
          for (int ni = 0; ni < 4; ++ni)
            acc[mi][ni] = __builtin_amdgcn_mfma_f32_16x16x32_bf16(
                af[mi], bf_[ni], acc[mi][ni], 0, 0, 0);
      }
    }
#pragma unroll
    for (int mi = 0; mi < 4; ++mi){
      int g = goff + mi*16 + fq*4;
      int grp = g >> 4;
#pragma unroll
      for (int ni = 0; ni < 4; ++ni){
        int r = r0 + roff + ni*16 + fr;
        int bt = r >> 6, s = r & 63;
        ushort4 st;
        st.x = f2b(acc[mi][ni][0]); st.y = f2b(acc[mi][ni][1]);
        st.z = f2b(acc[mi][ni][2]); st.w = f2b(acc[mi][ni][3]);
        *(ushort4*)&Pg[(size_t)bt*16384 + grp*1024 + s*16 + fq*4] = st;
      }
    }
    if (t < 128) qg[r0 + t] = qacc;
    __syncthreads();   // drains all waves' stores (vmcnt 0) before publish
    if (t == 0){
      __threadfence();
      __hip_atomic_store(&flags[bb*64 + tq2], 1,
                         __ATOMIC_RELEASE, __HIP_MEMORY_SCOPE_AGENT);
    }
    return;
  }

  // ================= CONSUMER =================
  const int b     = blockIdx.x;
  const int lane  = tid & 63;
  const int wave  = tid >> 6;          // 0..15
  const int g_loc = lane >> 2;
  const int fc    = lane & 3;
  const int gcol  = wave*16 + g_loc;
  const int f     = tid & 255;

  uint32_t wcp2[32];
#pragma unroll
  for (int i = 0; i < 16; ++i){
    int m  = (4*fc + i) & 15;
    int fb = fc*64 + m*4;
    wcp2[2*i]   = pack2(Wcg[(fb+0)*256 + gcol], Wcg[(fb+1)*256 + gcol]);
    wcp2[2*i+1] = pack2(Wcg[(fb+2)*256 + gcol], Wcg[(fb+3)*256 + gcol]);
  }

  if (tid < 256){
    sh.c.ctx[tid] = 0.f;
    sh.c.bbr[tid] = K2 * biasg[tid];
    sh.c.ur[tid]  = ug[tid];
    sh.c.wlc[tid] = Wlcg[tid];
  }
  if (tid < 4) sh.c.glc[tid] = 0.f;
  const float blf = blg[0];
  float glcr = 0.f;

  // deep prefetch of x(0) BEFORE the flag wait (x is input, always ready)
  const float4* pX = (const float4*)Xg + (size_t)(b*Tdim)*4096 + wave*256 + lane;
  float4 xA0 = pX[0], xA1 = pX[64], xA2 = pX[128], xA3 = pX[192];

  // wait for group 0 (bt 0,1 of this batch) before touching P/q
  if (tid == 0){
    while (__hip_atomic_load(&flags[b*64], __ATOMIC_ACQUIRE,
                             __HIP_MEMORY_SCOPE_AGENT) == 0)
      __builtin_amdgcn_s_sleep(4);
  }
  __syncthreads();   // consts visible + flag gate for all threads

  const u16*   pP = Pg + (size_t)(b*Tdim)*16384 + wave*1024 + lane*16;
  const float* pq = qg + (size_t)(b*Tdim)*64 + lane;

  uint32_t pw[8];
  {
    const uint4* pp_ = (const uint4*)pP;
    *(uint4*)&pw[0] = pp_[0]; *(uint4*)&pw[4] = pp_[1];
  }
  float qcur = pq[0];

  float* outO = out;
  float* outC = out + Bdim*Tdim*Fdim;
  float* outW = out + 2*Bdim*Tdim*Fdim;

  for (int tt = 0; tt < Tdim; ++tt){
    const int bt    = b*Tdim + tt;
    const int nstep = (tt < Tdim-1) ? 1 : 0;

    // ---- prefetch issues, all with >= 1 full step of cover ----
    uint32_t pwn[8];                             // P(t+1): used AB(t+1)
    {
      const uint4* pp_ = (const uint4*)(pP + (size_t)nstep*16384);
      *(uint4*)&pwn[0] = pp_[0]; *(uint4*)&pwn[4] = pp_[1];
    }
    float qn = pq[nstep*64];                     // q(t+1): used AB(t+1)
    const float4* pXn = pX + (size_t)nstep*4096; // x(t+1): used C(t+1)
    float4 xn0 = pXn[0], xn1 = pXn[64], xn2 = pXn[128], xn3 = pXn[192];

    // ================= AB (fused) =================
    {
      glcr += sh.c.glc[0] + sh.c.glc[1] + sh.c.glc[2] + sh.c.glc[3];
      float logit = glcr + blf + qcur;
      float sig = __builtin_amdgcn_rcpf(1.f + __builtin_exp2f(-LOG2E*logit));
      const float l2  = K2 * sig;
      const float l2b = K2 - K2*sig;

      // GEMV with 4 independent accumulators (breaks 256-cyc fma chain)
      float pa0 = 0.f, pa1 = 0.f, pa2 = 0.f, pa3 = 0.f;
#pragma unroll
      for (int i = 0; i < 16; ++i){
        int m = (4*fc + i) & 15;
        float4 cv = *(const float4*)&sh.c.ctx[fc*64 + m*4];
        pa0 = fmaf(cv.x, b2f_lo(wcp2[2*i]),   pa0);
        pa1 = fmaf(cv.y, b2f_hi(wcp2[2*i]),   pa1);
        pa2 = fmaf(cv.z, b2f_lo(wcp2[2*i+1]), pa2);
        pa3 = fmaf(cv.w, b2f_hi(wcp2[2*i+1]), pa3);
      }
      float pa = (pa0 + pa1) + (pa2 + pa3);
      pa += __shfl_xor(pa, 1, 64);
      pa += __shfl_xor(pa, 2, 64);
      float c[16];
#pragma unroll
      for (int j = 0; j < 16; ++j)
        c[j] = __shfl(pa, 4*j, 64);

      // tanh + ait partial, 2 accumulators
      float ait0 = 0.f, ait1 = 0.f;
#pragma unroll
      for (int j = 0; j < 16; ++j){
        float pv = (j & 1) ? b2f_hi(pw[j>>1]) : b2f_lo(pw[j>>1]);
        float bb = sh.c.bbr[wave*16 + j];
        float uu = sh.c.ur[wave*16 + j];
        float z  = fmaf(l2, pv, fmaf(l2b, c[j], bb));
        float e  = __builtin_exp2f(z);
        float r  = __builtin_amdgcn_rcpf(e + 1.f);
        if (j & 1) ait1 += fmaf(-2.f*uu, r, uu);
        else       ait0 += fmaf(-2.f*uu, r, uu);
      }
      sh.c.pp[lane*17 + wave] = ait0 + ait1;
    }
    bar_lds();                             // S1: pp visible

    // ================= C: MAXLESS softmax + attended =================
    {
      const int ppb = lane*17;
      float s0 = 0.f, s1 = 0.f, s2 = 0.f, s3 = 0.f;
#pragma unroll
      for (int k = 0; k < 4; ++k){
        s0 += sh.c.pp[ppb + 4*k + 0];
        s1 += sh.c.pp[ppb + 4*k + 1];
        s2 += sh.c.pp[ppb + 4*k + 2];
        s3 += sh.c.pp[ppb + 4*k + 3];
      }
      float ait = (s0 + s1) + (s2 + s3);
      // exactly reference: exp(ait) / (sum + eps), no max shift
      float e = __builtin_exp2f(LOG2E*ait);
      float ssum = e;
#pragma unroll
      for (int off = 32; off > 0; off >>= 1)
        ssum += __shfl_xor(ssum, off, 64);
      float a = e * __builtin_amdgcn_rcpf(ssum + 1e-7f);
      if (wave == 0) outW[(size_t)bt*Sdim + lane] = a;

      const float av0 = __shfl(a, wave*4 + 0, 64);
      const float av1 = __shfl(a, wave*4 + 1, 64);
      const float av2 = __shfl(a, wave*4 + 2, 64);
      const float av3 = __shfl(a, wave*4 + 3, 64);
      float4 acc;
      acc.x = av0*xA0.x; acc.y = av0*xA0.y; acc.z = av0*xA0.z; acc.w = av0*xA0.w;
      acc.x = fmaf(av1, xA1.x, acc.x); acc.y = fmaf(av1, xA1.y, acc.y);
      acc.z = fmaf(av1, xA1.z, acc.z); acc.w = fmaf(av1, xA1.w, acc.w);
      acc.x = fmaf(av2, xA2.x, acc.x); acc.y = fmaf(av2, xA2.y, acc.y);
      acc.z = fmaf(av2, xA2.z, acc.z); acc.w = fmaf(av2, xA2.w, acc.w);
      acc.x = fmaf(av3, xA3.x, acc.x); acc.y = fmaf(av3, xA3.y, acc.y);
      acc.z = fmaf(av3, xA3.z, acc.z); acc.w = fmaf(av3, xA3.w, acc.w);
      *(float4*)&sh.c.attp[wave*260 + lane*4] = acc;
    }
    bar_lds();                             // S2: attp visible

    // ================= D: reduce + ctx update + outputs =================
    if (tid < 256){
      float a0 = 0.f, a1 = 0.f, a2 = 0.f, a3 = 0.f;
#pragma unroll
      for (int k = 0; k < 4; ++k){
        a0 += sh.c.attp[(4*k+0)*260 + f];
        a1 += sh.c.attp[(4*k+1)*260 + f];
        a2 += sh.c.attp[(4*k+2)*260 + f];
        a3 += sh.c.attp[(4*k+3)*260 + f];
      }
      float att = (a0 + a1) + (a2 + a3);
      const size_t o = (size_t)bt*Fdim + f;
      outO[o] = att;
      float nc = sh.c.ctx[f] + att;
      sh.c.ctx[f] = nc;
      outC[o] = nc;
      float gp = att * sh.c.wlc[f];
#pragma unroll
      for (int off = 32; off > 0; off >>= 1)
        gp += __shfl_xor(gp, off, 64);
      if (lane == 0) sh.c.glc[wave] = gp;
    }
    // flag gate for next step's P(t+2) prefetch (group (tt+2)>>1), folded
    // before the existing S3 barrier -> zero extra barriers.
    if (tid == 0 && (tt & 1) == 0 && tt <= Tdim-4){
      const int g = (tt + 2) >> 1;
      while (__hip_atomic_load(&flags[b*64 + g], __ATOMIC_ACQUIRE,
                               __HIP_MEMORY_SCOPE_AGENT) == 0)
        __builtin_amdgcn_s_sleep(4);
    }
    bar_lds();                             // S3: ctx/glc visible, gate done

#pragma unroll
    for (int k = 0; k < 8; ++k) pw[k] = pwn[k];
    qcur = qn;
    xA0 = xn0; xA1 = xn1; xA2 = xn2; xA3 = xn3;
    pP += (size_t)nstep*16384;
    pX += (size_t)nstep*4096;
    pq += (size_t)nstep*64;
  }
}

// ===========================================================================
// FALLBACK (zero workspace) — the round-3 passing kernel, verbatim.
// ===========================================================================
__global__ __launch_bounds__(1024) void fused_ctx_attn(
    const float* __restrict__ Xg, const float* __restrict__ Wg,
    const float* __restrict__ Wcg, const float* __restrict__ Wlg,
    const float* __restrict__ Wlcg, const float* __restrict__ blg,
    const float* __restrict__ biasg, const float* __restrict__ ug,
    float* __restrict__ out)
{
  __shared__ u16   xs[64*272];
  __shared__ float ps[64*257];
  __shared__ float cpart[8*258];
  __shared__ float qp[64*5];
  __shared__ float pp[64*17];
  __shared__ float attp[4*260];
  __shared__ float ctx_s[256], c_s[256], bb_s[256], u_s[256], wlc_s[256], wl_s[256];
  __shared__ float l2_s[64], l2b_s[64], a_s[64];
  __shared__ float glc_p[4];

  const int tid  = threadIdx.x;
  const int b    = blockIdx.x;
  const int lane = tid & 63;
  const int wave = tid >> 6;
  const int fr   = lane & 15;
  const int fq   = lane >> 4;
  const int f    = tid & 255;
  const int sb   = tid >> 8;

  bf16x8 afW[8];
  {
    const int gcol = wave*16 + fr;
#pragma unroll
    for (int kt = 0; kt < 8; ++kt){
      u16 tmp[8];
#pragma unroll
      for (int j = 0; j < 8; ++j)
        tmp[j] = f2b(Wg[(kt*32 + fq*8 + j)*256 + gcol]);
      afW[kt] = *(const bf16x8*)tmp;
    }
  }
  const int fj = tid >> 7;
  const int gp = tid & 127;
  uint32_t wcp[32];
#pragma unroll
  for (int fi = 0; fi < 32; ++fi)
    wcp[fi] = pack2(Wcg[(fj*32 + fi)*256 + gp*2], Wcg[(fj*32 + fi)*256 + gp*2 + 1]);

  if (tid < 256){
    ctx_s[tid] = 0.f;
    bb_s[tid]  = K2 * biasg[tid];
    u_s[tid]   = ug[tid];
    wlc_s[tid] = Wlcg[tid];
    wl_s[tid]  = Wlg[tid];
  }
  if (tid < 4) glc_p[tid] = 0.f;
  const float blf = blg[0];
  float glcr = 0.f;

  float* outO = out;
  float* outC = out + Bdim*Tdim*Fdim;
  float* outW = out + 2*Bdim*Tdim*Fdim;

  const int srow = tid >> 5;
  const int sc8  = (tid & 31)*8;
  {
    const long xb = (long)(b*Tdim)*Sdim*Fdim;
    const float4* p0 = (const float4*)&Xg[xb + (long)srow*256 + sc8];
    const float4* p1 = (const float4*)&Xg[xb + (long)(srow+32)*256 + sc8];
    *(uint4*)&xs[srow*272 + sc8]      = pack8(p0[0], p0[1]);
    *(uint4*)&xs[(srow+32)*272 + sc8] = pack8(p1[0], p1[1]);
  }
  __syncthreads();

  for (int tt = 0; tt < Tdim; ++tt){
    const int tn = (tt < Tdim-1) ? (tt+1) : tt;
    const long xb = (long)((b*Tdim + tn))*Sdim*Fdim;
    const float4* p0 = (const float4*)&Xg[xb + (long)srow*256 + sc8];
    const float4* p1 = (const float4*)&Xg[xb + (long)(srow+32)*256 + sc8];
    uint4 xr0 = pack8(p0[0], p0[1]);
    uint4 xr1 = pack8(p1[0], p1[1]);

    {
      float pa = 0.f, pb = 0.f;
#pragma unroll
      for (int fi = 0; fi < 32; ++fi){
        float cf = ctx_s[fj*32 + fi];
        pa = fmaf(cf, b2f_lo(wcp[fi]), pa);
        pb = fmaf(cf, b2f_hi(wcp[fi]), pb);
      }
      float2 st; st.x = pa; st.y = pb;
      *(float2*)&cpart[fj*258 + gp*2] = st;
    }
    {
      f32x4 acc[4];
#pragma unroll
      for (int nt = 0; nt < 4; ++nt) acc[nt] = (f32x4){0.f,0.f,0.f,0.f};
#pragma unroll
      for (int kt = 0; kt < 8; ++kt){
#pragma unroll
        for (int nt = 0; nt < 4; ++nt){
          bf16x8 bfx = *(const bf16x8*)&xs[(nt*16 + fr)*272 + kt*32 + fq*8];
          acc[nt] = __builtin_amdgcn_mfma_f32_16x16x32_bf16(afW[kt], bfx, acc[nt], 0, 0, 0);
        }
      }
#pragma unroll
      for (int nt = 0; nt < 4; ++nt){
        const int s = nt*16 + fr;
        const int g = wave*16 + fq*4;
        ps[s*257 + g + 0] = acc[nt][0];
        ps[s*257 + g + 1] = acc[nt][1];
        ps[s*257 + g + 2] = acc[nt][2];
        ps[s*257 + g + 3] = acc[nt][3];
      }
    }
    if (tid < 256){
      const int s = tid >> 2, qtr = tid & 3;
      float a = 0.f;
#pragma unroll
      for (int j = 0; j < 64; ++j)
        a = fmaf(b2f(xs[s*272 + qtr*64 + j]), wl_s[qtr*64 + j], a);
      qp[s*5 + qtr] = a;
    }
    __syncthreads();

    if (tid < 256){
      float a = 0.f;
#pragma unroll
      for (int k = 0; k < 8; ++k) a += cpart[k*258 + tid];
      c_s[tid] = a;
    }
    if (tid < 64){
      glcr += glc_p[0] + glc_p[1] + glc_p[2] + glc_p[3];
      float q = qp[tid*5] + qp[tid*5+1] + qp[tid*5+2] + qp[tid*5+3];
      float logit = glcr + blf + q;
      float sig = 1.f / (1.f + __builtin_exp2f(-LOG2E*logit));
      l2_s[tid]  = K2 * sig;
      l2b_s[tid] = K2 - K2*sig;
    }
    __syncthreads();

    {
      const float cf = c_s[f], bbf = bb_s[f], uf = u_s[f], n2 = -2.f*u_s[f];
#pragma unroll
      for (int i = 0; i < 16; ++i){
        const int s = sb*16 + i;
        float z2 = fmaf(l2_s[s], ps[s*257 + f], fmaf(l2b_s[s], cf, bbf));
        float e  = __builtin_exp2f(z2);
        float r  = 1.f / (e + 1.f);
        ps[s*257 + f] = fmaf(n2, r, uf);
      }
    }
    __syncthreads();

    {
      const int s = tid & 63, grp = tid >> 6;
      float a = 0.f;
#pragma unroll
      for (int k = 0; k < 16; ++k) a += ps[s*257 + grp*16 + k];
      pp[s*17 + grp] = a;
    }
    __syncthreads();

    if (tid < 64){
      const int s = tid;
      float ait = 0.f;
#pragma unroll
      for (int k = 0; k < 16; ++k) ait += pp[s*17 + k];
      float m = ait;
#pragma unroll
      for (int off = 32; off > 0; off >>= 1)
        m = fmaxf(m, __shfl_xor(m, off, 64));
      float e = __builtin_exp2f(LOG2E*(ait - m));
      float ssum = e;
#pragma unroll
      for (int off = 32; off > 0; off >>= 1)
        ssum += __shfl_xor(ssum, off, 64);
      float denom = ssum + 1e-7f * __builtin_exp2f(-LOG2E*m);
      float a = e / denom;
      a_s[s] = a;
      outW[(b*Tdim + tt)*Sdim + s] = a;
    }
    __syncthreads();

    {
      float ap = 0.f;
#pragma unroll
      for (int i = 0; i < 16; ++i){
        const int s = sb*16 + i;
        ap = fmaf(a_s[s], b2f(xs[s*272 + f]), ap);
      }
      attp[sb*260 + f] = ap;
    }
    __syncthreads();

    if (tid < 256){
      float att = attp[f] + attp[260+f] + attp[520+f] + attp[780+f];
      const int o = (b*Tdim + tt)*Fdim + f;
      outO[o] = att;
      float nc = ctx_s[f] + att;
      ctx_s[f] = nc;
      outC[o] = nc;
      float gpart = att * wlc_s[f];
#pragma unroll
      for (int off = 32; off > 0; off >>= 1)
        gpart += __shfl_xor(gpart, off, 64);
      if (lane == 0) glc_p[wave] = gpart;
    }
    *(uint4*)&xs[srow*272 + sc8] = xr0;
    *(uint4*)&xs[(srow+32)*272 + sc8] = xr1;
    __syncthreads();
  }
}

// ---------------------------------------------------------------------------
extern "C" void kernel_launch(void* const* d_in, const int* in_sizes, int n_in,
                              void* d_out, int out_size, void* d_ws, size_t ws_size,
                              hipStream_t stream){
  const float* x    = (const float*)d_in[0];
  const float* W    = (const float*)d_in[1];
  const float* Wc   = (const float*)d_in[2];
  const float* Wl   = (const float*)d_in[3];
  const float* Wlc  = (const float*)d_in[4];
  const float* bl   = (const float*)d_in[5];
  const float* bias = (const float*)d_in[6];
  const float* u    = (const float*)d_in[7];
  float* out = (float*)d_out;

  const size_t P_BYTES  = (size_t)4096*16384*2;   // 134217728
  const size_t Q_BYTES  = (size_t)262144*4;       // 1048576
  const size_t WT_BYTES = (size_t)256*256*2;      // 131072
  const size_t FL_BYTES = (size_t)2048*4;         // 8192
  const size_t NEED = P_BYTES + Q_BYTES + WT_BYTES + FL_BYTES;

  if (ws_size >= NEED){
    uint8_t* ws = (uint8_t*)d_ws;
    u16*   P     = (u16*)ws;
    float* q     = (float*)(ws + P_BYTES);
    u16*   Wt    = (u16*)(ws + P_BYTES + Q_BYTES);
    int*   flags = (int*)(ws + P_BYTES + Q_BYTES + WT_BYTES);
    kt_transpose_cvt<<<16, 256, 0, stream>>>(W, Wt, flags);
    kt_combined<<<NCONS + NPROD, 1024, 0, stream>>>(
        x, Wt, Wl, Wc, Wlc, bl, bias, u, P, q, flags, out);
  } else {
    fused_ctx_attn<<<Bdim, 1024, 0, stream>>>(x, W, Wc, Wl, Wlc, bl, bias, u, out);
  }
}